// Round 9
// baseline (185.361 us; speedup 1.0000x reference)
//
#include <hip/hip_runtime.h>
#include <hip/hip_fp16.h>
#include <math.h>

#define BATCH 8192
#define EMB 128
#define NTHREADS 512
#define NWAVES 8
#define ROWS 8      // batch rows per block (rows 8-15 of MFMA M are zero-padded)
#define CH 136      // chunk stride in halves: 16 rows * 8 + 8 pad (272B; quads decollide banks)
#define SLOT 32     // fixed candidate slots per tropical row (exact fallback if exceeded)

// ws half-offsets (dense fp16 weights)
#define OFF_E1W1 0        // 64x256
#define OFF_E1W2 16384    // 64x64
#define OFF_E2W1 20480    // 64x320
#define OFF_E2W2 40960    // 128x64
#define OFF_E3W1 49152    // 64x384
#define OFF_E3W2 73728    // 256x64
#define OFF_DW1  90112    // 64x128
#define OFF_DW2  98304    // 1x64
#define W_DENSE  98368
// uint region at ws + W_DENSE:
//   [0 .. 4095]     ent: packed candidates, row o at [o*SLOT], (j<<16 | fp16bits)
//   [4096 .. 4223]  cnt: true candidate count per row (may exceed SLOT)

typedef __attribute__((ext_vector_type(8))) _Float16 v8h;
typedef __attribute__((ext_vector_type(4))) float v4f;

// One 8-row tile per block, 8 waves. CODE overlays dead XB (union).
// ent/cnt are NOT staged (global broadcast reads in the tropical phase).
struct Smem {
    union {
        _Float16 XB[32 * CH];    // base, chunked MFMA-A layout
        _Float16 CODE[16 * CH];  // tropical out (XB dead by then)
    } U;                         // 8704 B
    _Float16 WC[56 * CH];        // chunked witness: w1 ch0-7, w2 ch8-23, w3 ch24-55
    _Float16 H[8 * CH];          // hidden, chunked
};  // 26112 B -> 4 blocks/CU (104 KB of 160 KB), 32 waves/CU

// ---------------- prepass ----------------
// Blocks 0..24: fp32->fp16 weight cvt. Blocks 25..32: candidate build,
// one wave per trop row, fixed SLOT slots (no atomics, no memset).
__global__ __launch_bounds__(1024) void prep_kernel(
    const float* __restrict__ s0, const float* __restrict__ s1,
    const float* __restrict__ s2, const float* __restrict__ s3,
    const float* __restrict__ s4, const float* __restrict__ s5,
    const float* __restrict__ s6, const float* __restrict__ s7,
    const float* __restrict__ trop, _Float16* __restrict__ ws)
{
    const int b = blockIdx.x;
    const int tid = threadIdx.x;
    if (b < 25) {
        const int idx4 = (b * 1024 + tid) * 4;
        if (idx4 >= W_DENSE) return;
        const float* src; int off;
        if      (idx4 < OFF_E1W2) { src = s0; off = OFF_E1W1; }
        else if (idx4 < OFF_E2W1) { src = s1; off = OFF_E1W2; }
        else if (idx4 < OFF_E2W2) { src = s2; off = OFF_E2W1; }
        else if (idx4 < OFF_E3W1) { src = s3; off = OFF_E2W2; }
        else if (idx4 < OFF_E3W2) { src = s4; off = OFF_E3W1; }
        else if (idx4 < OFF_DW1)  { src = s5; off = OFF_E3W2; }
        else if (idx4 < OFF_DW2)  { src = s6; off = OFF_DW1;  }
        else                      { src = s7; off = OFF_DW2;  }
        const float4 v = *(const float4*)(src + (idx4 - off));
        _Float16* dst = ws + idx4;
        dst[0] = (_Float16)v.x; dst[1] = (_Float16)v.y;
        dst[2] = (_Float16)v.z; dst[3] = (_Float16)v.w;
    } else {
        const int lane = tid & 63;
        const int wave = tid >> 6;
        const int o = (b - 25) * 16 + wave;   // 8 blocks x 16 waves = 128 rows
        if (o >= 128) return;
        unsigned int* base = (unsigned int*)(ws + W_DENSE);

        // wit in [0,1] (+fp16 slack) => only j with T[o,j] <= minT + 1.02 can
        // win the min-plus. Exact pruning.
        const float* row = trop + (size_t)o * 448;
        float vals[7];
        float mn = 1e30f;
        #pragma unroll
        for (int it = 0; it < 7; ++it) {
            vals[it] = row[lane + it * 64];
            mn = fminf(mn, vals[it]);
        }
        mn = fminf(mn, __shfl_xor(mn, 1, 64));
        mn = fminf(mn, __shfl_xor(mn, 2, 64));
        mn = fminf(mn, __shfl_xor(mn, 4, 64));
        mn = fminf(mn, __shfl_xor(mn, 8, 64));
        mn = fminf(mn, __shfl_xor(mn, 16, 64));
        mn = fminf(mn, __shfl_xor(mn, 32, 64));
        const float thr = mn + 1.02f;

        const unsigned long long ltmask = (1ull << lane) - 1ull;
        unsigned int pos0 = 0;
        #pragma unroll
        for (int it = 0; it < 7; ++it) {
            const bool sel = vals[it] <= thr;
            const unsigned long long m = __ballot(sel);
            if (sel) {
                const unsigned int pos = pos0 + (unsigned)__popcll(m & ltmask);
                if (pos < SLOT) {
                    const unsigned short hb =
                        __builtin_bit_cast(unsigned short, (_Float16)vals[it]);
                    base[o * SLOT + pos] = ((unsigned)(lane + it * 64) << 16) | hb;
                }
            }
            pos0 += (unsigned)__popcll(m);
        }
        if (lane == 0) base[4096 + o] = pos0;
    }
}

// ---------------- one 16-o dense job (M=16 MFMA rows) ----------------
template <int K, int O, int ACT>
__device__ __forceinline__ void dense_job(
    const _Float16* __restrict__ Wg, const float* __restrict__ bias,
    const _Float16* A0, _Float16* OutC, int jid, int lane)
{
    constexpr int STEPS = K / 32;
    static_assert(STEPS % 2 == 0, "even steps");
    const int l15 = lane & 15;
    const int quad = lane >> 4;
    const int o = jid * 16 + l15;
    const _Float16* wrow = Wg + (size_t)o * K + quad * 8;
    v4f c0 = {0.f, 0.f, 0.f, 0.f};
    v4f c1 = {0.f, 0.f, 0.f, 0.f};
    #pragma unroll
    for (int s = 0; s < STEPS; s += 2) {
        const v8h a0 = *(const v8h*)(A0 + (s * 4 + quad) * CH + l15 * 8);
        const v8h b0 = *(const v8h*)(wrow + s * 32);
        const v8h a1 = *(const v8h*)(A0 + ((s + 1) * 4 + quad) * CH + l15 * 8);
        const v8h b1 = *(const v8h*)(wrow + (s + 1) * 32);
        c0 = __builtin_amdgcn_mfma_f32_16x16x32_f16(a0, b0, c0, 0, 0, 0);
        c1 = __builtin_amdgcn_mfma_f32_16x16x32_f16(a1, b1, c1, 0, 0, 0);
    }
    const v4f c = c0 + c1;
    const float bs = bias[o];
    #pragma unroll
    for (int i = 0; i < 4; ++i) {
        float vv = c[i] + bs;
        if (ACT == 0) vv = fmaxf(vv, 0.f);
        else          vv = 1.f / (1.f + __expf(-vv));
        OutC[(o >> 3) * CH + (quad * 4 + i) * 8 + (o & 7)] = (_Float16)vv;
    }
}

// ---------------- base GEMM (K=256 slice), returns c + bias ----------------
__device__ __forceinline__ v4f base_gemm(
    const _Float16* __restrict__ ws, const _Float16* XB, int tgt, int nt,
    int lane, const float* __restrict__ b1, const float* __restrict__ b2,
    const float* __restrict__ b3)
{
    const int l15 = lane & 15;
    const int quad = lane >> 4;
    const int o = nt * 16 + l15;
    const _Float16* wrow;
    const float* bias;
    if (tgt == 0)      { wrow = ws + OFF_E1W1 + (size_t)o * 256; bias = b1; }
    else if (tgt == 1) { wrow = ws + OFF_E2W1 + (size_t)o * 320; bias = b2; }
    else               { wrow = ws + OFF_E3W1 + (size_t)o * 384; bias = b3; }
    wrow += quad * 8;
    v4f c0 = {0.f, 0.f, 0.f, 0.f};
    v4f c1 = {0.f, 0.f, 0.f, 0.f};
    #pragma unroll
    for (int s = 0; s < 8; s += 2) {
        const v8h a0 = *(const v8h*)(XB + (s * 4 + quad) * CH + l15 * 8);
        const v8h b0 = *(const v8h*)(wrow + s * 32);
        const v8h a1 = *(const v8h*)(XB + ((s + 1) * 4 + quad) * CH + l15 * 8);
        const v8h b1v = *(const v8h*)(wrow + (s + 1) * 32);
        c0 = __builtin_amdgcn_mfma_f32_16x16x32_f16(a0, b0, c0, 0, 0, 0);
        c1 = __builtin_amdgcn_mfma_f32_16x16x32_f16(a1, b1v, c1, 0, 0, 0);
    }
    v4f c = c0 + c1;
    const float bs = bias[o];
    #pragma unroll
    for (int i = 0; i < 4; ++i) c[i] += bs;
    return c;
}

// ---------------- witness-part job with register-held fp32 C-init ----------------
template <int KW, int RS>
__device__ __forceinline__ void addpb_job(
    const _Float16* __restrict__ Wg, const _Float16* A0,
    const v4f hold, _Float16* OutH, int jid, int lane)
{
    constexpr int STEPS = KW / 32;      // 2 or 4
    static_assert(STEPS % 2 == 0, "even steps");
    const int l15 = lane & 15;
    const int quad = lane >> 4;
    const int o = jid * 16 + l15;
    const _Float16* wrow = Wg + (size_t)o * RS + quad * 8;
    v4f c0 = hold;
    v4f c1 = {0.f, 0.f, 0.f, 0.f};
    #pragma unroll
    for (int s = 0; s < STEPS; s += 2) {
        const v8h a0 = *(const v8h*)(A0 + (s * 4 + quad) * CH + l15 * 8);
        const v8h b0 = *(const v8h*)(wrow + s * 32);
        const v8h a1 = *(const v8h*)(A0 + ((s + 1) * 4 + quad) * CH + l15 * 8);
        const v8h b1 = *(const v8h*)(wrow + (s + 1) * 32);
        c0 = __builtin_amdgcn_mfma_f32_16x16x32_f16(a0, b0, c0, 0, 0, 0);
        c1 = __builtin_amdgcn_mfma_f32_16x16x32_f16(a1, b1, c1, 0, 0, 0);
    }
    const v4f c = c0 + c1;
    #pragma unroll
    for (int i = 0; i < 4; ++i) {
        const float vv = fmaxf(c[i], 0.f);
        OutH[(o >> 3) * CH + (quad * 4 + i) * 8 + (o & 7)] = (_Float16)vv;
    }
}

// ---------------- fused forward: 8 rows/block, 8 waves, 4 blocks/CU ----------------
__global__ __launch_bounds__(NTHREADS, 8) void tacit_fused_kernel(
    const int* __restrict__ u, const int* __restrict__ v,
    const float* __restrict__ emb,
    const float* __restrict__ e1_b1, const float* __restrict__ e1_b2,
    const float* __restrict__ e2_b1, const float* __restrict__ e2_b2,
    const float* __restrict__ e3_b1, const float* __restrict__ e3_b2,
    const float* __restrict__ dec_b1, const float* __restrict__ dec_b2,
    const float* __restrict__ trop,
    const _Float16* __restrict__ ws,
    float* __restrict__ out)
{
    __shared__ Smem S;
    const int tid = threadIdx.x;
    const int lane = tid & 63;
    const int wave = tid >> 6;          // 0..7
    const int row0 = blockIdx.x * ROWS;

    // ---- Stage 0: base embeddings rows 0-7; zero-fill MFMA rows 8-15 ----
    if (tid < 256) {
        const int row = tid & 7;
        const int kq = tid >> 3;                 // 0..31 (0-15 u, 16-31 v)
        const int node = (kq < 16) ? u[row0 + row] : v[row0 + row];
        const int col = (kq & 15) * 8;
        const float4 f0 = *(const float4*)(emb + (size_t)node * EMB + col);
        const float4 f1 = *(const float4*)(emb + (size_t)node * EMB + col + 4);
        v8h hv;
        hv[0] = (_Float16)f0.x; hv[1] = (_Float16)f0.y;
        hv[2] = (_Float16)f0.z; hv[3] = (_Float16)f0.w;
        hv[4] = (_Float16)f1.x; hv[5] = (_Float16)f1.y;
        hv[6] = (_Float16)f1.z; hv[7] = (_Float16)f1.w;
        *(v8h*)&S.U.XB[kq * CH + row * 8] = hv;
    } else {
        const int t = tid - 256;
        const int row = 8 + (t & 7);
        const int kq = t >> 3;
        v8h z = {(_Float16)0.f, (_Float16)0.f, (_Float16)0.f, (_Float16)0.f,
                 (_Float16)0.f, (_Float16)0.f, (_Float16)0.f, (_Float16)0.f};
        *(v8h*)&S.U.XB[kq * CH + row * 8] = z;
    }
    __syncthreads();

    // ---- Stage A: 12 base-GEMM jobs over 8 waves (1.5 rounds) ----
    // waves 0-3: H1 (store) then e3-partial (hold3, reg); waves 4-7: e2-partial (hold2, reg)
    v4f hold2 = {0.f, 0.f, 0.f, 0.f};
    v4f hold3 = {0.f, 0.f, 0.f, 0.f};
    if (wave < 4) {
        const v4f c = base_gemm(ws, S.U.XB, 0, wave, lane, e1_b1, e2_b1, e3_b1);
        const int l15 = lane & 15;
        const int quad = lane >> 4;
        const int o = wave * 16 + l15;
        #pragma unroll
        for (int i = 0; i < 4; ++i)
            S.H[(o >> 3) * CH + (quad * 4 + i) * 8 + (o & 7)] =
                (_Float16)fmaxf(c[i], 0.f);
        hold3 = base_gemm(ws, S.U.XB, 2, wave, lane, e1_b1, e2_b1, e3_b1);
    } else {
        hold2 = base_gemm(ws, S.U.XB, 1, wave - 4, lane, e1_b1, e2_b1, e3_b1);
    }
    __syncthreads();

    // ---- Stage B: w1 = sig(H1 @ e1w2^T + b) -> WC ch0-7 (waves 4-7) ----
    if (wave >= 4)
        dense_job<64, 64, 1>(ws + OFF_E1W2, e1_b2, S.H, S.WC, wave - 4, lane);
    __syncthreads();

    // ---- Stage C: H2 = relu(hold2 + w1 @ e2w1[:,256:]^T) (waves 4-7) ----
    if (wave >= 4)
        addpb_job<64, 320>(ws + OFF_E2W1 + 256, S.WC, hold2, S.H, wave - 4, lane);
    __syncthreads();

    // ---- Stage D: w2 = sig(H2 @ e2w2^T + b) -> WC ch8-23 (all 8 waves) ----
    dense_job<64, 128, 1>(ws + OFF_E2W2, e2_b2, S.H, S.WC + 8 * CH, wave, lane);
    __syncthreads();

    // ---- Stage E: H3 = relu(hold3 + w2 @ e3w1[:,256:]^T) (waves 0-3) ----
    if (wave < 4)
        addpb_job<128, 384>(ws + OFF_E3W1 + 256, S.WC + 8 * CH, hold3, S.H, wave, lane);
    __syncthreads();

    // ---- Stage F: w3 = sig(H3 @ e3w2^T + b) -> WC ch24-55 (8 waves x 2) ----
    dense_job<64, 256, 1>(ws + OFF_E3W2, e3_b2, S.H, S.WC + 24 * CH, wave, lane);
    dense_job<64, 256, 1>(ws + OFF_E3W2, e3_b2, S.H, S.WC + 24 * CH, wave + 8, lane);
    __syncthreads();

    // ---- Stage G: tropical, 8 waves x 16 o's (two octets), 8-way ILP ----
    // ent/cnt read straight from global (same-address broadcast across the
    // 16 lanes of each cp group; L2-resident). Witness from chunked WC:
    // wit[r][j] = WC[(j>>3)*CH + r*8 + (j&7)].
    {
        const unsigned int* entg = (const unsigned int*)(ws + W_DENSE);
        const unsigned int* cntg = entg + 4096;
        const int r = lane & 15;
        const int cp = lane >> 4;
        const _Float16* wr8 = &S.WC[r * 8];
        #pragma unroll 1
        for (int oo = 0; oo < 2; ++oo) {
            const int ob = wave * 16 + oo * 8;
            float acc[8];
            int idx8[8], end8[8];
            #pragma unroll
            for (int i = 0; i < 8; ++i) {
                const int o = ob + i;
                const int n = (int)cntg[o];
                idx8[i] = o * SLOT + cp;
                end8[i] = o * SLOT + (n < SLOT ? n : SLOT);
                acc[i] = 1e30f;
            }
            bool any = true;
            while (any) {
                any = false;
                #pragma unroll
                for (int i = 0; i < 8; ++i) {
                    if (idx8[i] < end8[i]) {
                        const unsigned int cwv = entg[idx8[i]];
                        const int j = (int)(cwv >> 16);
                        const float tv = (float)__builtin_bit_cast(
                            _Float16, (unsigned short)(cwv & 0xffffu));
                        acc[i] = fminf(acc[i], (float)wr8[(j >> 3) * CH + (j & 7)] + tv);
                        idx8[i] += 4;
                        any = true;
                    }
                }
            }
            // exact fallback for overflowed rows (uniform branch, ~never taken)
            #pragma unroll
            for (int i = 0; i < 8; ++i) {
                const int o = ob + i;
                if ((int)cntg[o] > SLOT) {
                    const float* trow = trop + (size_t)o * 448;
                    for (int j = cp; j < 448; j += 4)
                        acc[i] = fminf(acc[i],
                                       (float)wr8[(j >> 3) * CH + (j & 7)] + trow[j]);
                }
            }
            #pragma unroll
            for (int i = 0; i < 8; ++i) {
                float a = acc[i];
                a = fminf(a, __shfl_xor(a, 16, 64));
                a = fminf(a, __shfl_xor(a, 32, 64));
                if (cp == 0) {
                    const int o = ob + i;
                    S.U.CODE[(o >> 3) * CH + r * 8 + (o & 7)] = (_Float16)a;
                }
            }
        }
    }
    __syncthreads();

    // ---- Stage H: decoder 1, CODE(128) -> H(64) relu (waves 4-7) ----
    if (wave >= 4)
        dense_job<128, 64, 0>(ws + OFF_DW1, dec_b1, S.U.CODE, S.H, wave - 4, lane);
    __syncthreads();

    // ---- Stage I: decoder 2, H(64) -> scalar (wave 0, 4-way k-split) ----
    if (tid < 64) {
        const int r = lane & 15;
        const int part = lane >> 4;          // chunks part and part+4
        const _Float16* w2 = ws + OFF_DW2;
        float s = 0.f;
        #pragma unroll
        for (int q = 0; q < 2; ++q) {
            const int c = part + q * 4;
            const v8h hr = *(const v8h*)(&S.H[c * CH + r * 8]);
            const v8h wr = *(const v8h*)(w2 + c * 8);
            #pragma unroll
            for (int t = 0; t < 8; ++t) s += (float)hr[t] * (float)wr[t];
        }
        s += __shfl_xor(s, 16, 64);
        s += __shfl_xor(s, 32, 64);
        if (part == 0 && r < ROWS) out[row0 + r] = s + dec_b2[0];
    }
}

extern "C" void kernel_launch(void* const* d_in, const int* in_sizes, int n_in,
                              void* d_out, int out_size, void* d_ws, size_t ws_size,
                              hipStream_t stream) {
    const int*   u      = (const int*)d_in[0];
    const int*   v      = (const int*)d_in[1];
    const float* emb    = (const float*)d_in[2];
    const float* e1_w1  = (const float*)d_in[3];
    const float* e1_b1  = (const float*)d_in[4];
    const float* e1_w2  = (const float*)d_in[5];
    const float* e1_b2  = (const float*)d_in[6];
    const float* e2_w1  = (const float*)d_in[7];
    const float* e2_b1  = (const float*)d_in[8];
    const float* e2_w2  = (const float*)d_in[9];
    const float* e2_b2  = (const float*)d_in[10];
    const float* e3_w1  = (const float*)d_in[11];
    const float* e3_b1  = (const float*)d_in[12];
    const float* e3_w2  = (const float*)d_in[13];
    const float* e3_b2  = (const float*)d_in[14];
    const float* trop_w = (const float*)d_in[15];
    const float* dec_w1 = (const float*)d_in[16];
    const float* dec_b1 = (const float*)d_in[17];
    const float* dec_w2 = (const float*)d_in[18];
    const float* dec_b2 = (const float*)d_in[19];
    float* out = (float*)d_out;
    _Float16* ws = (_Float16*)d_ws;

    // two dispatches: prepass (weight cvt + fixed-slot candidate build),
    // then fused forward (8 rows/block, 8-wave barrier domains, 4 blocks/CU:
    // 32 waves/CU with 4 independent pipelines hiding each other's bubbles)
    prep_kernel<<<33, 1024, 0, stream>>>(
        e1_w1, e1_w2, e2_w1, e2_w2, e3_w1, e3_w2, dec_w1, dec_w2, trop_w, ws);

    tacit_fused_kernel<<<BATCH / ROWS, NTHREADS, 0, stream>>>(
        u, v, emb,
        e1_b1, e1_b2, e2_b1, e2_b2, e3_b1, e3_b2, dec_b1, dec_b2,
        trop_w, ws, out);
}

// Round 10
// 172.022 us; speedup vs baseline: 1.0775x; 1.0775x over previous
//
#include <hip/hip_runtime.h>
#include <hip/hip_fp16.h>
#include <math.h>

#define BATCH 8192
#define EMB 128
#define TILE 16
#define NTHREADS 1024
#define NWAVES 16
#define CH 136      // chunk stride in halves: 16 rows * 8 + 8 pad (272B; quads decollide banks)
#define SLOT 32     // fixed candidate slots per tropical row (exact fallback if exceeded)

typedef __attribute__((ext_vector_type(8))) _Float16 v8h;
typedef __attribute__((ext_vector_type(4))) float v4f;

// Single-dispatch: weights read as fp32 with inline RTN cvt (identical values
// to the old prepass cvt); candidate table built in LDS by IDLE waves of the
// low-utilization stages (hidden under stage latency). No workspace use.
struct Smem {
    union {
        _Float16 XB[32 * CH];    // base, chunked MFMA-A layout
        _Float16 CODE[16 * CH];  // tropical out (XB dead by then)
    } U;                         // 8704 B
    _Float16 WC[56 * CH];        // chunked witness: w1 ch0-7, w2 ch8-23, w3 ch24-55
    _Float16 H[8 * CH];          // hidden, chunked
    unsigned int ent[128 * SLOT];// packed candidates (j<<16 | fp16bits(T[o][j]))
    unsigned int cnt[128];       // true candidate count per row
};  // 43008 B -> 2 blocks/CU (thread-bound), 32 waves/CU

__device__ __forceinline__ v8h load8f(const float* __restrict__ p) {
    const float4 a = *(const float4*)p;
    const float4 b = *(const float4*)(p + 4);
    v8h r;
    r[0] = (_Float16)a.x; r[1] = (_Float16)a.y;
    r[2] = (_Float16)a.z; r[3] = (_Float16)a.w;
    r[4] = (_Float16)b.x; r[5] = (_Float16)b.y;
    r[6] = (_Float16)b.z; r[7] = (_Float16)b.w;
    return r;
}

// ---- build one trop row's candidate list into LDS (whole wave) ----
// wit in [0,1] (+fp16 slack) => only j with T[o,j] <= minT + 1.02 can win
// the min-plus. Exact pruning; overflow rows fall back to full scan in G.
__device__ __forceinline__ void build_row(
    const float* __restrict__ trop, int o, int lane,
    unsigned int* __restrict__ ent, unsigned int* __restrict__ cnt)
{
    const float* row = trop + (size_t)o * 448;
    float vals[7];
    float mn = 1e30f;
    #pragma unroll
    for (int it = 0; it < 7; ++it) {
        vals[it] = row[lane + it * 64];
        mn = fminf(mn, vals[it]);
    }
    mn = fminf(mn, __shfl_xor(mn, 1, 64));
    mn = fminf(mn, __shfl_xor(mn, 2, 64));
    mn = fminf(mn, __shfl_xor(mn, 4, 64));
    mn = fminf(mn, __shfl_xor(mn, 8, 64));
    mn = fminf(mn, __shfl_xor(mn, 16, 64));
    mn = fminf(mn, __shfl_xor(mn, 32, 64));
    const float thr = mn + 1.02f;

    const unsigned long long ltmask = (1ull << lane) - 1ull;
    unsigned int pos0 = 0;
    #pragma unroll
    for (int it = 0; it < 7; ++it) {
        const bool sel = vals[it] <= thr;
        const unsigned long long m = __ballot(sel);
        if (sel) {
            const unsigned int pos = pos0 + (unsigned)__popcll(m & ltmask);
            if (pos < SLOT) {
                const unsigned short hb =
                    __builtin_bit_cast(unsigned short, (_Float16)vals[it]);
                ent[o * SLOT + pos] = ((unsigned)(lane + it * 64) << 16) | hb;
            }
        }
        pos0 += (unsigned)__popcll(m);
    }
    if (lane == 0) cnt[o] = pos0;
}

// ---------------- one 16-o dense job (M=16 rows), fp32 weights ----------------
template <int K, int ACT>
__device__ __forceinline__ void dense_job(
    const float* __restrict__ Wg, const float* __restrict__ bias,
    const _Float16* A0, _Float16* OutC, int jid, int lane)
{
    constexpr int STEPS = K / 32;
    static_assert(STEPS % 2 == 0, "even steps");
    const int l15 = lane & 15;
    const int quad = lane >> 4;
    const int o = jid * 16 + l15;
    const float* wrow = Wg + (size_t)o * K + quad * 8;
    v4f c0 = {0.f, 0.f, 0.f, 0.f};
    v4f c1 = {0.f, 0.f, 0.f, 0.f};
    #pragma unroll
    for (int s = 0; s < STEPS; s += 2) {
        const v8h a0 = *(const v8h*)(A0 + (s * 4 + quad) * CH + l15 * 8);
        const v8h b0 = load8f(wrow + s * 32);
        const v8h a1 = *(const v8h*)(A0 + ((s + 1) * 4 + quad) * CH + l15 * 8);
        const v8h b1 = load8f(wrow + (s + 1) * 32);
        c0 = __builtin_amdgcn_mfma_f32_16x16x32_f16(a0, b0, c0, 0, 0, 0);
        c1 = __builtin_amdgcn_mfma_f32_16x16x32_f16(a1, b1, c1, 0, 0, 0);
    }
    const v4f c = c0 + c1;
    const float bs = bias[o];
    #pragma unroll
    for (int i = 0; i < 4; ++i) {
        float vv = c[i] + bs;
        if (ACT == 0) vv = fmaxf(vv, 0.f);
        else          vv = 1.f / (1.f + __expf(-vv));
        OutC[(o >> 3) * CH + (quad * 4 + i) * 8 + (o & 7)] = (_Float16)vv;
    }
}

// ---------------- base GEMM (K=256 slice), fp32 weights, returns c+bias ----------------
__device__ __forceinline__ v4f base_gemm(
    const _Float16* XB, int tgt, int nt, int lane,
    const float* __restrict__ w1g, const float* __restrict__ w2g,
    const float* __restrict__ w3g,
    const float* __restrict__ b1, const float* __restrict__ b2,
    const float* __restrict__ b3)
{
    const int l15 = lane & 15;
    const int quad = lane >> 4;
    const int o = nt * 16 + l15;
    const float* wrow;
    const float* bias;
    if (tgt == 0)      { wrow = w1g + (size_t)o * 256; bias = b1; }
    else if (tgt == 1) { wrow = w2g + (size_t)o * 320; bias = b2; }
    else               { wrow = w3g + (size_t)o * 384; bias = b3; }
    wrow += quad * 8;
    v4f c0 = {0.f, 0.f, 0.f, 0.f};
    v4f c1 = {0.f, 0.f, 0.f, 0.f};
    #pragma unroll
    for (int s = 0; s < 8; s += 2) {
        const v8h a0 = *(const v8h*)(XB + (s * 4 + quad) * CH + l15 * 8);
        const v8h b0 = load8f(wrow + s * 32);
        const v8h a1 = *(const v8h*)(XB + ((s + 1) * 4 + quad) * CH + l15 * 8);
        const v8h b1v = load8f(wrow + (s + 1) * 32);
        c0 = __builtin_amdgcn_mfma_f32_16x16x32_f16(a0, b0, c0, 0, 0, 0);
        c1 = __builtin_amdgcn_mfma_f32_16x16x32_f16(a1, b1v, c1, 0, 0, 0);
    }
    v4f c = c0 + c1;
    const float bs = bias[o];
    #pragma unroll
    for (int i = 0; i < 4; ++i) c[i] += bs;
    return c;
}

// ---------------- witness-part job with register-held fp32 C-init ----------------
template <int KW, int RS>
__device__ __forceinline__ void addpb_job(
    const float* __restrict__ Wg, const _Float16* A0,
    const v4f hold, _Float16* OutH, int jid, int lane)
{
    constexpr int STEPS = KW / 32;      // 2 or 4
    static_assert(STEPS % 2 == 0, "even steps");
    const int l15 = lane & 15;
    const int quad = lane >> 4;
    const int o = jid * 16 + l15;
    const float* wrow = Wg + (size_t)o * RS + quad * 8;
    v4f c0 = hold;
    v4f c1 = {0.f, 0.f, 0.f, 0.f};
    #pragma unroll
    for (int s = 0; s < STEPS; s += 2) {
        const v8h a0 = *(const v8h*)(A0 + (s * 4 + quad) * CH + l15 * 8);
        const v8h b0 = load8f(wrow + s * 32);
        const v8h a1 = *(const v8h*)(A0 + ((s + 1) * 4 + quad) * CH + l15 * 8);
        const v8h b1 = load8f(wrow + (s + 1) * 32);
        c0 = __builtin_amdgcn_mfma_f32_16x16x32_f16(a0, b0, c0, 0, 0, 0);
        c1 = __builtin_amdgcn_mfma_f32_16x16x32_f16(a1, b1, c1, 0, 0, 0);
    }
    const v4f c = c0 + c1;
    #pragma unroll
    for (int i = 0; i < 4; ++i) {
        const float vv = fmaxf(c[i], 0.f);
        OutH[(o >> 3) * CH + (quad * 4 + i) * 8 + (o & 7)] = (_Float16)vv;
    }
}

// ---------------- single fused kernel: 16 rows/block, 16 waves ----------------
__global__ __launch_bounds__(NTHREADS, 8) void tacit_fused_kernel(
    const int* __restrict__ u, const int* __restrict__ v,
    const float* __restrict__ emb,
    const float* __restrict__ e1_w1, const float* __restrict__ e1_b1,
    const float* __restrict__ e1_w2, const float* __restrict__ e1_b2,
    const float* __restrict__ e2_w1, const float* __restrict__ e2_b1,
    const float* __restrict__ e2_w2, const float* __restrict__ e2_b2,
    const float* __restrict__ e3_w1, const float* __restrict__ e3_b1,
    const float* __restrict__ e3_w2, const float* __restrict__ e3_b2,
    const float* __restrict__ trop,
    const float* __restrict__ dec_w1, const float* __restrict__ dec_b1,
    const float* __restrict__ dec_w2, const float* __restrict__ dec_b2,
    float* __restrict__ out)
{
    __shared__ Smem S;
    const int tid = threadIdx.x;
    const int lane = tid & 63;
    const int wave = tid >> 6;          // 0..15
    const int row0 = blockIdx.x * TILE;

    // ---- Stage 0: emb gather (waves 0-7) || build rows 0-15 (waves 8-15) ----
    if (tid < 512) {
        const int row = tid & 15;
        const int kq = tid >> 4;                 // 0..31 (0-15 u, 16-31 v)
        const int node = (kq < 16) ? u[row0 + row] : v[row0 + row];
        const int col = (kq & 15) * 8;
        const float4 f0 = *(const float4*)(emb + (size_t)node * EMB + col);
        const float4 f1 = *(const float4*)(emb + (size_t)node * EMB + col + 4);
        v8h hv;
        hv[0] = (_Float16)f0.x; hv[1] = (_Float16)f0.y;
        hv[2] = (_Float16)f0.z; hv[3] = (_Float16)f0.w;
        hv[4] = (_Float16)f1.x; hv[5] = (_Float16)f1.y;
        hv[6] = (_Float16)f1.z; hv[7] = (_Float16)f1.w;
        *(v8h*)&S.U.XB[kq * CH + row * 8] = hv;
    } else {
        const int b0r = (wave - 8) * 2;          // rows 0..15
        build_row(trop, b0r,     lane, S.ent, S.cnt);
        build_row(trop, b0r + 1, lane, S.ent, S.cnt);
    }
    __syncthreads();

    // ---- Stage A: base GEMMs (waves 0-11) || build rows 16-31 (waves 12-15) ----
    // tgt0 (w0-3): H1 = relu(base@e1w1^T+b) -> H; tgt1 (w4-7): hold2 (reg);
    // tgt2 (w8-11): hold3 (reg).
    v4f hold2 = {0.f, 0.f, 0.f, 0.f};
    v4f hold3 = {0.f, 0.f, 0.f, 0.f};
    if (wave < 12) {
        const int tgt = wave >> 2;
        const v4f c = base_gemm(S.U.XB, tgt, wave & 3, lane,
                                e1_w1, e2_w1, e3_w1, e1_b1, e2_b1, e3_b1);
        if (tgt == 0) {
            const int l15 = lane & 15;
            const int quad = lane >> 4;
            const int o = (wave & 3) * 16 + l15;
            #pragma unroll
            for (int i = 0; i < 4; ++i)
                S.H[(o >> 3) * CH + (quad * 4 + i) * 8 + (o & 7)] =
                    (_Float16)fmaxf(c[i], 0.f);
        } else if (tgt == 1) {
            hold2 = c;
        } else {
            hold3 = c;
        }
    } else {
        const int b0r = 16 + (wave - 12) * 4;    // rows 16..31
        #pragma unroll
        for (int t = 0; t < 4; ++t) build_row(trop, b0r + t, lane, S.ent, S.cnt);
    }
    __syncthreads();

    // ---- Stage B: w1 (waves 0-3) || build rows 32-79 (waves 4-15) ----
    if (wave < 4) {
        dense_job<64, 1>(e1_w2, e1_b2, S.H, S.WC, wave, lane);
    } else {
        const int b0r = 32 + (wave - 4) * 4;     // rows 32..79
        #pragma unroll
        for (int t = 0; t < 4; ++t) build_row(trop, b0r + t, lane, S.ent, S.cnt);
    }
    __syncthreads();

    // ---- Stage C: H2 (waves 4-7, hold2) || build rows 80-127 (other 12) ----
    if (wave >= 4 && wave < 8) {
        addpb_job<64, 320>(e2_w1 + 256, S.WC, hold2, S.H, wave - 4, lane);
    } else {
        const int idx = (wave < 4) ? wave : (wave - 4);   // 0..11
        const int b0r = 80 + idx * 4;            // rows 80..127
        #pragma unroll
        for (int t = 0; t < 4; ++t) build_row(trop, b0r + t, lane, S.ent, S.cnt);
    }
    __syncthreads();

    // ---- Stage D: w2 -> WC ch8-23 (waves 0-3, 12-15; holds untouched) ----
    {
        const int dnt = (wave < 4) ? wave : (wave >= 12 ? wave - 8 : -1);
        if (dnt >= 0)
            dense_job<64, 1>(e2_w2, e2_b2, S.H, S.WC + 8 * CH, dnt, lane);
    }
    __syncthreads();

    // ---- Stage E: H3 = relu(hold3 + w2 @ e3w1[:,256:]^T) (waves 8-11) ----
    if (wave >= 8 && wave < 12)
        addpb_job<128, 384>(e3_w1 + 256, S.WC + 8 * CH, hold3, S.H, wave - 8, lane);
    __syncthreads();

    // ---- Stage F: w3 = sig(H3 @ e3w2^T + b) -> WC ch24-55 (all 16 waves) ----
    dense_job<64, 1>(e3_w2, e3_b2, S.H, S.WC + 24 * CH, wave, lane);
    __syncthreads();

    // ---- Stage G: tropical via exact ragged candidate pruning, 8-way ILP ----
    // wave covers o-octet; lane = (r = lane&15, cp = lane>>4). Witness from
    // chunked WC: wit[r][j] = WC[(j>>3)*CH + r*8 + (j&7)]. fp32 mins.
    {
        const int r = lane & 15;
        const int cp = lane >> 4;
        const _Float16* wr8 = &S.WC[r * 8];
        float acc[8];
        int idx8[8], end8[8];
        #pragma unroll
        for (int i = 0; i < 8; ++i) {
            const int o = (wave << 3) + i;
            const int n = (int)S.cnt[o];
            idx8[i] = o * SLOT + cp;
            end8[i] = o * SLOT + (n < SLOT ? n : SLOT);
            acc[i] = 1e30f;
        }
        bool any = true;
        while (any) {
            any = false;
            #pragma unroll
            for (int i = 0; i < 8; ++i) {
                if (idx8[i] < end8[i]) {
                    const unsigned int cwv = S.ent[idx8[i]];
                    const int j = (int)(cwv >> 16);
                    const float tv = (float)__builtin_bit_cast(
                        _Float16, (unsigned short)(cwv & 0xffffu));
                    acc[i] = fminf(acc[i], (float)wr8[(j >> 3) * CH + (j & 7)] + tv);
                    idx8[i] += 4;
                    any = true;
                }
            }
        }
        // exact fallback for overflowed rows (uniform branch, ~never taken)
        #pragma unroll
        for (int i = 0; i < 8; ++i) {
            const int o = (wave << 3) + i;
            if ((int)S.cnt[o] > SLOT) {
                const float* trow = trop + (size_t)o * 448;
                for (int j = cp; j < 448; j += 4)
                    acc[i] = fminf(acc[i],
                                   (float)wr8[(j >> 3) * CH + (j & 7)] + trow[j]);
            }
        }
        #pragma unroll
        for (int i = 0; i < 8; ++i) {
            float a = acc[i];
            a = fminf(a, __shfl_xor(a, 16, 64));
            a = fminf(a, __shfl_xor(a, 32, 64));
            if (cp == 0) {
                const int o = (wave << 3) + i;
                S.U.CODE[(o >> 3) * CH + r * 8 + (o & 7)] = (_Float16)a;
            }
        }
    }
    __syncthreads();

    // ---- Stage H: decoder 1, CODE(128) -> H(64) relu (waves 0-3) ----
    if (wave < 4)
        dense_job<128, 0>(dec_w1, dec_b1, S.U.CODE, S.H, wave, lane);
    __syncthreads();

    // ---- Stage I: decoder 2, H(64) -> scalar (wave 0, 4-way k-split) ----
    if (tid < 64) {
        const int r = lane & 15;
        const int part = lane >> 4;          // chunks part and part+4
        float s = 0.f;
        #pragma unroll
        for (int q = 0; q < 2; ++q) {
            const int c = part + q * 4;
            const v8h hr = *(const v8h*)(&S.H[c * CH + r * 8]);
            const float4 w0 = *(const float4*)(dec_w2 + c * 8);
            const float4 w1 = *(const float4*)(dec_w2 + c * 8 + 4);
            s += (float)hr[0] * w0.x + (float)hr[1] * w0.y
               + (float)hr[2] * w0.z + (float)hr[3] * w0.w
               + (float)hr[4] * w1.x + (float)hr[5] * w1.y
               + (float)hr[6] * w1.z + (float)hr[7] * w1.w;
        }
        s += __shfl_xor(s, 16, 64);
        s += __shfl_xor(s, 32, 64);
        if (part == 0) out[row0 + r] = s + dec_b2[0];
    }
}

extern "C" void kernel_launch(void* const* d_in, const int* in_sizes, int n_in,
                              void* d_out, int out_size, void* d_ws, size_t ws_size,
                              hipStream_t stream) {
    const int*   u      = (const int*)d_in[0];
    const int*   v      = (const int*)d_in[1];
    const float* emb    = (const float*)d_in[2];
    const float* e1_w1  = (const float*)d_in[3];
    const float* e1_b1  = (const float*)d_in[4];
    const float* e1_w2  = (const float*)d_in[5];
    const float* e1_b2  = (const float*)d_in[6];
    const float* e2_w1  = (const float*)d_in[7];
    const float* e2_b1  = (const float*)d_in[8];
    const float* e2_w2  = (const float*)d_in[9];
    const float* e2_b2  = (const float*)d_in[10];
    const float* e3_w1  = (const float*)d_in[11];
    const float* e3_b1  = (const float*)d_in[12];
    const float* e3_w2  = (const float*)d_in[13];
    const float* e3_b2  = (const float*)d_in[14];
    const float* trop_w = (const float*)d_in[15];
    const float* dec_w1 = (const float*)d_in[16];
    const float* dec_b1 = (const float*)d_in[17];
    const float* dec_w2 = (const float*)d_in[18];
    const float* dec_b2 = (const float*)d_in[19];
    float* out = (float*)d_out;
    (void)d_ws; (void)ws_size;

    // single dispatch: inline fp32->fp16 weight cvt in the MFMA B-load path;
    // candidate build hidden in idle waves of stages 0/A/B/C. No workspace.
    tacit_fused_kernel<<<BATCH / TILE, NTHREADS, 0, stream>>>(
        u, v, emb,
        e1_w1, e1_b1, e1_w2, e1_b2,
        e2_w1, e2_b1, e2_w2, e2_b2,
        e3_w1, e3_b1, e3_w2, e3_b2,
        trop_w, dec_w1, dec_b1, dec_w2, dec_b2,
        out);
}

// Round 11
// 145.951 us; speedup vs baseline: 1.2700x; 1.1786x over previous
//
#include <hip/hip_runtime.h>
#include <hip/hip_fp16.h>
#include <math.h>

#define BATCH 8192
#define EMB 128
#define TILE 16
#define NTHREADS 1024
#define NWAVES 16
#define CH 136      // chunk stride in halves: 16 rows * 8 + 8 pad (272B; quads decollide banks)
#define WITS 450    // row-major WIT stride (halves): 900B -> 225 words (odd) -> full bank spread
#define ENT_CAP 4096

// ws half-offsets (dense fp16 weights)
#define OFF_E1W1 0        // 64x256
#define OFF_E1W2 16384    // 64x64
#define OFF_E2W1 20480    // 64x320
#define OFF_E2W2 40960    // 128x64
#define OFF_E3W1 49152    // 64x384
#define OFF_E3W2 73728    // 256x64
#define OFF_DW1  90112    // 64x128
#define OFF_DW2  98304    // 1x64
#define W_DENSE  98368
// candidate region (uint32s, based at ws + W_DENSE):
//   [0..127]   per-row packed (count<<16 | beg)
//   [131]      allocation counter (memset to 0 pre-launch)
//   [132 ...]  packed entries (j<<16 | fp16bits(T[o][j])), ragged by o

typedef __attribute__((ext_vector_type(8))) _Float16 v8h;
typedef __attribute__((ext_vector_type(4))) float v4f;

struct Smem {
    _Float16 XB[32 * CH];        // base, chunked MFMA-A layout
    _Float16 W12C[24 * CH];      // w1 chunks 0-7, w2 chunks 8-23 (chunked)
    _Float16 H[8 * CH];          // hidden, chunked
    _Float16 CODE[16 * CH];      // tropical out, chunked
    _Float16 WITrm[TILE * WITS]; // wit row-major for the gather
    unsigned int ent[ENT_CAP];
    unsigned int off[132];
};

// ---------------- prepass ----------------
// Blocks 0..24: fp32->fp16 cvt (1024-wide).
// Blocks 25..32: wave-parallel candidate build, one wave per trop row,
// slot allocation via device-scope atomicAdd (no barriers, single pass).
__global__ __launch_bounds__(1024) void prep_kernel(
    const float* __restrict__ s0, const float* __restrict__ s1,
    const float* __restrict__ s2, const float* __restrict__ s3,
    const float* __restrict__ s4, const float* __restrict__ s5,
    const float* __restrict__ s6, const float* __restrict__ s7,
    const float* __restrict__ trop, _Float16* __restrict__ ws)
{
    const int b = blockIdx.x;
    const int tid = threadIdx.x;
    if (b < 25) {
        const int idx4 = (b * 1024 + tid) * 4;
        if (idx4 >= W_DENSE) return;
        const float* src; int off;
        if      (idx4 < OFF_E1W2) { src = s0; off = OFF_E1W1; }
        else if (idx4 < OFF_E2W1) { src = s1; off = OFF_E1W2; }
        else if (idx4 < OFF_E2W2) { src = s2; off = OFF_E2W1; }
        else if (idx4 < OFF_E3W1) { src = s3; off = OFF_E2W2; }
        else if (idx4 < OFF_E3W2) { src = s4; off = OFF_E3W1; }
        else if (idx4 < OFF_DW1)  { src = s5; off = OFF_E3W2; }
        else if (idx4 < OFF_DW2)  { src = s6; off = OFF_DW1;  }
        else                      { src = s7; off = OFF_DW2;  }
        const float4 v = *(const float4*)(src + (idx4 - off));
        _Float16* dst = ws + idx4;
        dst[0] = (_Float16)v.x; dst[1] = (_Float16)v.y;
        dst[2] = (_Float16)v.z; dst[3] = (_Float16)v.w;
    } else {
        const int lane = tid & 63;
        const int wave = tid >> 6;
        const int o = (b - 25) * 16 + wave;   // 8 blocks x 16 waves = 128 rows
        if (o >= 128) return;
        unsigned int* base = (unsigned int*)(ws + W_DENSE);
        unsigned int* counter = base + 131;

        const float* row = trop + (size_t)o * 448;
        float vals[7];
        float mn = 1e30f;
        #pragma unroll
        for (int it = 0; it < 7; ++it) {
            vals[it] = row[lane + it * 64];
            mn = fminf(mn, vals[it]);
        }
        mn = fminf(mn, __shfl_xor(mn, 1, 64));
        mn = fminf(mn, __shfl_xor(mn, 2, 64));
        mn = fminf(mn, __shfl_xor(mn, 4, 64));
        mn = fminf(mn, __shfl_xor(mn, 8, 64));
        mn = fminf(mn, __shfl_xor(mn, 16, 64));
        mn = fminf(mn, __shfl_xor(mn, 32, 64));
        // wit in [0,1] (+fp16 slack) => only j with T[o,j] <= minT + 1.02
        // can win the min-plus. Exact pruning.
        const float thr = mn + 1.02f;

        unsigned long long masks[7];
        unsigned int n = 0;
        #pragma unroll
        for (int it = 0; it < 7; ++it) {
            masks[it] = __ballot(vals[it] <= thr);
            n += (unsigned)__popcll(masks[it]);
        }
        unsigned int beg = 0;
        if (lane == 0) beg = atomicAdd(counter, n);
        beg = (unsigned)__shfl((int)beg, 0, 64);
        if (lane == 0) base[o] = (n << 16) | (beg & 0xffffu);

        unsigned int done = beg;
        const unsigned long long ltmask = (1ull << lane) - 1ull;
        #pragma unroll
        for (int it = 0; it < 7; ++it) {
            const unsigned long long m = masks[it];
            if (vals[it] <= thr) {
                const unsigned int pos = done + (unsigned)__popcll(m & ltmask);
                if (pos < ENT_CAP) {
                    const unsigned short hb =
                        __builtin_bit_cast(unsigned short, (_Float16)vals[it]);
                    base[132 + pos] = ((unsigned)(lane + it * 64) << 16) | hb;
                }
            }
            done += (unsigned)__popcll(m);
        }
    }
}

// ---------------- MFMA dense layer (M=16 rows) ----------------
// D[m][o] = act(bias[o] + sum_k A[m][k]*W[o][k]). A chunked in LDS
// (A0 first STEPS0 steps, then A1); W row-major [O][K] in global.
// Dual accumulators (STEPS is always even) halve the dependent-MFMA chain.
template <int K, int STEPS0, int O, int ACT, bool CHUNKW, bool RMW>
__device__ __forceinline__ void dense_mfma(
    const _Float16* __restrict__ Wg, const float* __restrict__ bias,
    const _Float16* A0, const _Float16* A1,
    _Float16* OutC, _Float16* OutRM, int rmbase, int wave, int lane)
{
    constexpr int STEPS = K / 32;
    static_assert(STEPS % 2 == 0, "even steps");
    constexpr int NJOBS = O / 16;
    const int l15 = lane & 15;
    const int quad = lane >> 4;

    for (int nt = wave; nt < NJOBS; nt += NWAVES) {
        v4f c0 = {0.f, 0.f, 0.f, 0.f};
        v4f c1 = {0.f, 0.f, 0.f, 0.f};
        const _Float16* wrow = Wg + (size_t)(nt * 16 + l15) * K + quad * 8;
        #pragma unroll
        for (int s = 0; s < STEPS; s += 2) {
            const int g0 = s * 4 + quad;
            const int g1 = (s + 1) * 4 + quad;
            const _Float16* a0p = (s < STEPS0)
                ? (A0 + g0 * CH + l15 * 8)
                : (A1 + (g0 - STEPS0 * 4) * CH + l15 * 8);
            const _Float16* a1p = ((s + 1) < STEPS0)
                ? (A0 + g1 * CH + l15 * 8)
                : (A1 + (g1 - STEPS0 * 4) * CH + l15 * 8);
            const v8h a0 = *(const v8h*)a0p;
            const v8h b0 = *(const v8h*)(wrow + s * 32);
            const v8h a1 = *(const v8h*)a1p;
            const v8h b1 = *(const v8h*)(wrow + (s + 1) * 32);
            c0 = __builtin_amdgcn_mfma_f32_16x16x32_f16(a0, b0, c0, 0, 0, 0);
            c1 = __builtin_amdgcn_mfma_f32_16x16x32_f16(a1, b1, c1, 0, 0, 0);
        }
        const v4f c = c0 + c1;
        const int o = nt * 16 + l15;                      // C/D col = lane&15
        const float bs = bias[o];
        #pragma unroll
        for (int i = 0; i < 4; ++i) {                     // C/D row = quad*4+reg
            float vv = c[i] + bs;
            if (ACT == 0) vv = fmaxf(vv, 0.f);
            else          vv = 1.f / (1.f + __expf(-vv));
            const int m = quad * 4 + i;
            const _Float16 hv = (_Float16)vv;
            if (CHUNKW) OutC[(o >> 3) * CH + m * 8 + (o & 7)] = hv;
            if (RMW)    OutRM[m * WITS + rmbase + o] = hv;
        }
    }
}

// ---------------- fused forward ----------------
__global__ __launch_bounds__(NTHREADS, 8) void tacit_fused_kernel(
    const int* __restrict__ u, const int* __restrict__ v,
    const float* __restrict__ emb,
    const float* __restrict__ e1_b1, const float* __restrict__ e1_b2,
    const float* __restrict__ e2_b1, const float* __restrict__ e2_b2,
    const float* __restrict__ e3_b1, const float* __restrict__ e3_b2,
    const float* __restrict__ dec_b1, const float* __restrict__ dec_b2,
    const _Float16* __restrict__ ws,
    float* __restrict__ out)
{
    __shared__ Smem S;
    const int tid = threadIdx.x;
    const int lane = tid & 63;
    const int wave = tid >> 6;
    const int row0 = blockIdx.x * TILE;

    // ---- Stage candidate tables; gather + cvt into chunked XB ----
    {
        const unsigned int* base = (const unsigned int*)(ws + W_DENSE);
        if (tid < 33) *(uint4*)&S.off[tid * 4] = *(const uint4*)(base + tid * 4);
        *(uint4*)&S.ent[tid * 4] = *(const uint4*)(base + 132 + tid * 4);
    }
    if (tid < 512) {
        const int row = tid & 15;
        const int kq = tid >> 4;                 // 0..31 (0-15 u, 16-31 v)
        const int node = (kq < 16) ? u[row0 + row] : v[row0 + row];
        const int col = (kq & 15) * 8;
        const float4 f0 = *(const float4*)(emb + (size_t)node * EMB + col);
        const float4 f1 = *(const float4*)(emb + (size_t)node * EMB + col + 4);
        v8h hv;
        hv[0] = (_Float16)f0.x; hv[1] = (_Float16)f0.y;
        hv[2] = (_Float16)f0.z; hv[3] = (_Float16)f0.w;
        hv[4] = (_Float16)f1.x; hv[5] = (_Float16)f1.y;
        hv[6] = (_Float16)f1.z; hv[7] = (_Float16)f1.w;
        *(v8h*)&S.XB[kq * CH + row * 8] = hv;
    }
    __syncthreads();

    // ---- Witness 1 ----
    dense_mfma<256, 8, 64, 0, true, false>(ws + OFF_E1W1, e1_b1, S.XB, nullptr,
                                           S.H, nullptr, 0, wave, lane);
    __syncthreads();
    dense_mfma<64, 2, 64, 1, true, true>(ws + OFF_E1W2, e1_b2, S.H, nullptr,
                                         S.W12C, S.WITrm, 0, wave, lane);
    __syncthreads();

    // ---- Witness 2 ----
    dense_mfma<320, 8, 64, 0, true, false>(ws + OFF_E2W1, e2_b1, S.XB, S.W12C,
                                           S.H, nullptr, 0, wave, lane);
    __syncthreads();
    dense_mfma<64, 2, 128, 1, true, true>(ws + OFF_E2W2, e2_b2, S.H, nullptr,
                                          S.W12C + 8 * CH, S.WITrm, 64, wave, lane);
    __syncthreads();

    // ---- Witness 3 ----
    dense_mfma<384, 8, 64, 0, true, false>(ws + OFF_E3W1, e3_b1, S.XB, S.W12C + 8 * CH,
                                           S.H, nullptr, 0, wave, lane);
    __syncthreads();
    dense_mfma<64, 2, 256, 1, false, true>(ws + OFF_E3W2, e3_b2, S.H, nullptr,
                                           nullptr, S.WITrm, 192, wave, lane);
    __syncthreads();

    // ---- Tropical via exact ragged candidate pruning, 8-way ILP ----
    // wave covers o-octet; lane = (r = lane&15, cp = lane>>4). The 8 o's
    // advance in lockstep so 8 independent ent->wrow load chains are in
    // flight per iteration (vs 1 in the serial form). fp32 mins.
    {
        const int r = lane & 15;
        const int cp = lane >> 4;
        const _Float16* wrow = &S.WITrm[r * WITS];
        float acc[8];
        int idx[8], end8[8];
        #pragma unroll
        for (int i = 0; i < 8; ++i) {
            const int o = (wave << 3) + i;
            const unsigned int tb = S.off[o];
            const int beg = (int)(tb & 0xffffu);
            int e = beg + (int)(tb >> 16);
            e = e < ENT_CAP ? e : ENT_CAP;
            idx[i] = beg + cp;
            end8[i] = e;
            acc[i] = 1e30f;
        }
        bool any = true;
        while (any) {
            any = false;
            #pragma unroll
            for (int i = 0; i < 8; ++i) {
                if (idx[i] < end8[i]) {
                    const unsigned int cwv = S.ent[idx[i]];
                    const int j = (int)(cwv >> 16);
                    const float tv = (float)__builtin_bit_cast(
                        _Float16, (unsigned short)(cwv & 0xffffu));
                    acc[i] = fminf(acc[i], (float)wrow[j] + tv);
                    idx[i] += 4;
                    any = true;
                }
            }
        }
        #pragma unroll
        for (int i = 0; i < 8; ++i) {
            float a = acc[i];
            a = fminf(a, __shfl_xor(a, 16, 64));
            a = fminf(a, __shfl_xor(a, 32, 64));
            if (cp == 0) {
                const int o = (wave << 3) + i;
                S.CODE[(o >> 3) * CH + r * 8 + (o & 7)] = (_Float16)a;
            }
        }
    }
    __syncthreads();

    // ---- Decoder 1: CODE(128) -> H(64) relu ----
    dense_mfma<128, 4, 64, 0, true, false>(ws + OFF_DW1, dec_b1, S.CODE, nullptr,
                                           S.H, nullptr, 0, wave, lane);
    __syncthreads();

    // ---- Decoder 2: H(64) -> scalar; wave 0, 4-way k-split per row ----
    if (tid < 64) {
        const int r = lane & 15;
        const int part = lane >> 4;          // chunks part and part+4
        const _Float16* w2 = ws + OFF_DW2;
        float s = 0.f;
        #pragma unroll
        for (int q = 0; q < 2; ++q) {
            const int c = part + q * 4;
            const v8h hr = *(const v8h*)(&S.H[c * CH + r * 8]);
            const v8h wr = *(const v8h*)(w2 + c * 8);
            #pragma unroll
            for (int t = 0; t < 8; ++t) s += (float)hr[t] * (float)wr[t];
        }
        s += __shfl_xor(s, 16, 64);
        s += __shfl_xor(s, 32, 64);
        if (part == 0) out[row0 + r] = s + dec_b2[0];
    }
}

extern "C" void kernel_launch(void* const* d_in, const int* in_sizes, int n_in,
                              void* d_out, int out_size, void* d_ws, size_t ws_size,
                              hipStream_t stream) {
    const int*   u      = (const int*)d_in[0];
    const int*   v      = (const int*)d_in[1];
    const float* emb    = (const float*)d_in[2];
    const float* e1_w1  = (const float*)d_in[3];
    const float* e1_b1  = (const float*)d_in[4];
    const float* e1_w2  = (const float*)d_in[5];
    const float* e1_b2  = (const float*)d_in[6];
    const float* e2_w1  = (const float*)d_in[7];
    const float* e2_b1  = (const float*)d_in[8];
    const float* e2_w2  = (const float*)d_in[9];
    const float* e2_b2  = (const float*)d_in[10];
    const float* e3_w1  = (const float*)d_in[11];
    const float* e3_b1  = (const float*)d_in[12];
    const float* e3_w2  = (const float*)d_in[13];
    const float* e3_b2  = (const float*)d_in[14];
    const float* trop_w = (const float*)d_in[15];
    const float* dec_w1 = (const float*)d_in[16];
    const float* dec_b1 = (const float*)d_in[17];
    const float* dec_w2 = (const float*)d_in[18];
    const float* dec_b2 = (const float*)d_in[19];
    float* out = (float*)d_out;
    _Float16* ws = (_Float16*)d_ws;

    // zero the candidate-slot allocation counter (uint at W_DENSE + 131)
    hipMemsetAsync((char*)d_ws + (size_t)W_DENSE * 2 + 131 * 4, 0, 4, stream);

    prep_kernel<<<33, 1024, 0, stream>>>(
        e1_w1, e1_w2, e2_w1, e2_w2, e3_w1, e3_w2, dec_w1, dec_w2, trop_w, ws);

    tacit_fused_kernel<<<BATCH / TILE, NTHREADS, 0, stream>>>(
        u, v, emb,
        e1_b1, e1_b2, e2_b1, e2_b2, e3_b1, e3_b2, dec_b1, dec_b2,
        ws, out);
}